// Round 1
// baseline (1019.930 us; speedup 1.0000x reference)
//
#include <hip/hip_runtime.h>
#include <cstdint>
#include <cstddef>

#define NFRAMES 8192
#define MDIM    1024
#define TILE    128
#define BK      32
#define Q_SCALE 0.06f

typedef __bf16 bf16x8 __attribute__((ext_vector_type(8)));
typedef float  f32x4  __attribute__((ext_vector_type(4)));

// fp32 -> bf16 round-to-nearest-even on raw bits
__device__ __forceinline__ unsigned short f2bf(float f) {
  union { float f; uint32_t u; } a; a.f = f;
  uint32_t u = a.u;
  u += 0x7FFFu + ((u >> 16) & 1u);
  return (unsigned short)(u >> 16);
}

// async global->LDS, 16B per lane; lds dest must be wave-uniform base (HW adds lane*16)
__device__ __forceinline__ void async_ld16(const void* g, void* l) {
  __builtin_amdgcn_global_load_lds(
      (const __attribute__((address_space(1))) void*)(uintptr_t)g,
      (__attribute__((address_space(3))) void*)(uint32_t)(uintptr_t)l,
      16, 0, 0);
}

__device__ __forceinline__ void store_val(float* p, float v) { *p = v; }
__device__ __forceinline__ void store_val(unsigned short* p, float v) { *p = f2bf(v); }

// C[M_ x N_] = A[M_ x K_] * B[N_ x K_]^T  (all row-major, bf16 inputs, fp32 acc)
// m97-style: 128x128 tile, 4 waves in 2x2, each wave 4x4 grid of 16x16x32 MFMA.
template <typename OutT>
__global__ __launch_bounds__(256) void gemm_bt(
    const unsigned short* __restrict__ A, const unsigned short* __restrict__ B,
    OutT* __restrict__ C, int M_, int N_, int K_, float scale)
{
  __shared__ alignas(16) unsigned short As[TILE * BK]; // [row][k] row-major, 8KB
  __shared__ alignas(16) unsigned short Bs[TILE * BK]; // [col][k] row-major, 8KB

  const int tid  = threadIdx.x;
  const int wave = tid >> 6;
  const int lane = tid & 63;
  const int m0 = blockIdx.y * TILE;
  const int n0 = blockIdx.x * TILE;
  const int wm = (wave >> 1) * 64;   // wave row offset in tile
  const int wn = (wave & 1) * 64;    // wave col offset in tile

  f32x4 acc[4][4] = {};

  // staging: chunk q in [0,512) covers 128 rows x 4 chunks of 8 bf16 (16B)
  const int q1 = wave * 64 + lane;        // issue 0
  const int q2 = q1 + 256;                // issue 1
  const int r1 = q1 >> 2, c1 = (q1 & 3) << 3;
  const int r2 = q2 >> 2, c2 = (q2 & 3) << 3;

  const int fr = lane & 15;   // row-in-16 (A) / col-in-16 (B) / output col
  const int fq = lane >> 4;   // k-chunk quad / output row quad

  for (int k0 = 0; k0 < K_; k0 += BK) {
    __syncthreads();
    async_ld16(A + (size_t)(m0 + r1) * K_ + k0 + c1, As + wave * 512);
    async_ld16(B + (size_t)(n0 + r1) * K_ + k0 + c1, Bs + wave * 512);
    async_ld16(A + (size_t)(m0 + r2) * K_ + k0 + c2, As + 2048 + wave * 512);
    async_ld16(B + (size_t)(n0 + r2) * K_ + k0 + c2, Bs + 2048 + wave * 512);
    __syncthreads();  // implies s_waitcnt vmcnt(0): LDS tiles complete

    bf16x8 af[4], bfr[4];
#pragma unroll
    for (int i = 0; i < 4; ++i)
      af[i] = *(const bf16x8*)&As[(wm + i * 16 + fr) * BK + fq * 8];
#pragma unroll
    for (int j = 0; j < 4; ++j)
      bfr[j] = *(const bf16x8*)&Bs[(wn + j * 16 + fr) * BK + fq * 8];
#pragma unroll
    for (int i = 0; i < 4; ++i)
#pragma unroll
      for (int j = 0; j < 4; ++j)
        acc[i][j] = __builtin_amdgcn_mfma_f32_16x16x32_bf16(af[i], bfr[j], acc[i][j], 0, 0, 0);
  }

  // C/D layout (verified m89/m91): col = lane&15, row = (lane>>4)*4 + reg
#pragma unroll
  for (int i = 0; i < 4; ++i)
#pragma unroll
    for (int j = 0; j < 4; ++j)
#pragma unroll
      for (int r = 0; r < 4; ++r) {
        int row = m0 + wm + i * 16 + fq * 4 + r;
        int col = n0 + wn + j * 16 + fr;
        store_val(&C[(size_t)row * N_ + col], acc[i][j][r] * scale);
      }
}

// one block per row: softmax over 8192 cols + dropout mask, write bf16 P
__global__ __launch_bounds__(256) void softmax_dropout_kernel(
    const float* __restrict__ S, const float* __restrict__ U,
    unsigned short* __restrict__ P)
{
  const int row = blockIdx.x;
  const float4*  s4 = (const float4*)(S + (size_t)row * NFRAMES);
  const float4*  u4 = (const float4*)(U + (size_t)row * NFRAMES);
  ushort4*       p4 = (ushort4*)(P + (size_t)row * NFRAMES);
  const int tid = threadIdx.x;
  const int lane = tid & 63, wave = tid >> 6;

  float v[32];
  float mx = -3.4e38f;
#pragma unroll
  for (int j = 0; j < 8; ++j) {
    float4 t = s4[j * 256 + tid];
    v[j*4+0] = t.x; v[j*4+1] = t.y; v[j*4+2] = t.z; v[j*4+3] = t.w;
    mx = fmaxf(mx, fmaxf(fmaxf(t.x, t.y), fmaxf(t.z, t.w)));
  }
#pragma unroll
  for (int o = 32; o > 0; o >>= 1) mx = fmaxf(mx, __shfl_xor(mx, o));
  __shared__ float redm[4];
  __shared__ float reds[4];
  if (lane == 0) redm[wave] = mx;
  __syncthreads();
  mx = fmaxf(fmaxf(redm[0], redm[1]), fmaxf(redm[2], redm[3]));

  float sum = 0.f;
#pragma unroll
  for (int i = 0; i < 32; ++i) { v[i] = __expf(v[i] - mx); sum += v[i]; }
#pragma unroll
  for (int o = 32; o > 0; o >>= 1) sum += __shfl_xor(sum, o);
  if (lane == 0) reds[wave] = sum;
  __syncthreads();
  sum = reds[0] + reds[1] + reds[2] + reds[3];
  float inv = 1.0f / sum;

#pragma unroll
  for (int j = 0; j < 8; ++j) {
    float4 t = u4[j * 256 + tid];
    ushort4 o;
    o.x = f2bf(v[j*4+0] * inv * (t.x >= 0.5f ? 2.0f : 0.0f));
    o.y = f2bf(v[j*4+1] * inv * (t.y >= 0.5f ? 2.0f : 0.0f));
    o.z = f2bf(v[j*4+2] * inv * (t.z >= 0.5f ? 2.0f : 0.0f));
    o.w = f2bf(v[j*4+3] * inv * (t.w >= 0.5f ? 2.0f : 0.0f));
    p4[j * 256 + tid] = o;
  }
}

__global__ void cvt_f32_bf16(const float* __restrict__ in,
                             unsigned short* __restrict__ out, int n4)
{
  int i = blockIdx.x * blockDim.x + threadIdx.x;
  if (i < n4) {
    float4 t = ((const float4*)in)[i];
    ushort4 o;
    o.x = f2bf(t.x); o.y = f2bf(t.y); o.z = f2bf(t.z); o.w = f2bf(t.w);
    ((ushort4*)out)[i] = o;
  }
}

extern "C" void kernel_launch(void* const* d_in, const int* in_sizes, int n_in,
                              void* d_out, int out_size, void* d_ws, size_t ws_size,
                              hipStream_t stream) {
  const float* x  = (const float*)d_in[0];
  const float* Wk = (const float*)d_in[1];
  const float* Wq = (const float*)d_in[2];
  const float* Wv = (const float*)d_in[3];
  const float* Wo = (const float*)d_in[4];
  const float* u  = (const float*)d_in[5];
  float* out = (float*)d_out;

  const int N = NFRAMES, M = MDIM;
  char* base = (char*)d_ws;
  size_t off = 0;
  auto alloc = [&](size_t bytes) -> void* {
    void* p = base + off; off += (bytes + 255) & ~(size_t)255; return p;
  };
  unsigned short* xb  = (unsigned short*)alloc((size_t)N * M * 2);
  unsigned short* wkb = (unsigned short*)alloc((size_t)M * M * 2);
  unsigned short* wqb = (unsigned short*)alloc((size_t)M * M * 2);
  unsigned short* wvb = (unsigned short*)alloc((size_t)M * M * 2);
  unsigned short* wob = (unsigned short*)alloc((size_t)M * M * 2);
  unsigned short* Qb  = (unsigned short*)alloc((size_t)N * M * 2);
  unsigned short* Kb  = (unsigned short*)alloc((size_t)N * M * 2);
  unsigned short* Vt  = (unsigned short*)alloc((size_t)N * M * 2);  // [M x N] = V^T
  unsigned short* yb  = (unsigned short*)alloc((size_t)N * M * 2);

  // stripe size R over query rows, sized to fit S (fp32 RxN) + P (bf16 RxN) in ws
  size_t avail = ws_size > off ? ws_size - off : 0;
  int R = 128;
  const int cands[7] = {8192, 4096, 2048, 1024, 512, 256, 128};
  for (int ci = 0; ci < 7; ++ci) {
    size_t need = (size_t)cands[ci] * N * 4 + 256 + (size_t)cands[ci] * N * 2 + 256;
    if (need <= avail) { R = cands[ci]; break; }
  }
  float*          Sb = (float*)alloc((size_t)R * N * 4);
  unsigned short* Pb = (unsigned short*)alloc((size_t)R * N * 2);

  // 1. convert inputs to bf16
  cvt_f32_bf16<<<(N * M / 4 + 255) / 256, 256, 0, stream>>>(x,  xb,  N * M / 4);
  cvt_f32_bf16<<<(M * M / 4 + 255) / 256, 256, 0, stream>>>(Wk, wkb, M * M / 4);
  cvt_f32_bf16<<<(M * M / 4 + 255) / 256, 256, 0, stream>>>(Wq, wqb, M * M / 4);
  cvt_f32_bf16<<<(M * M / 4 + 255) / 256, 256, 0, stream>>>(Wv, wvb, M * M / 4);
  cvt_f32_bf16<<<(M * M / 4 + 255) / 256, 256, 0, stream>>>(Wo, wob, M * M / 4);

  // 2. projections: K = x Wk^T, Q = 0.06 * x Wq^T, V^T = Wv x^T (computed as gemm_bt(Wv, x))
  gemm_bt<unsigned short><<<dim3(M / TILE, N / TILE), 256, 0, stream>>>(xb, wkb, Kb, N, M, M, 1.0f);
  gemm_bt<unsigned short><<<dim3(M / TILE, N / TILE), 256, 0, stream>>>(xb, wqb, Qb, N, M, M, Q_SCALE);
  gemm_bt<unsigned short><<<dim3(N / TILE, M / TILE), 256, 0, stream>>>(wvb, xb, Vt, M, N, M, 1.0f);

  // 3. attention in row stripes: S = Q K^T -> softmax+dropout -> y = P V
  for (int i0 = 0; i0 < N; i0 += R) {
    gemm_bt<float><<<dim3(N / TILE, R / TILE), 256, 0, stream>>>(
        Qb + (size_t)i0 * M, Kb, Sb, R, N, M, 1.0f);
    softmax_dropout_kernel<<<R, 256, 0, stream>>>(Sb, u + (size_t)i0 * N, Pb);
    gemm_bt<unsigned short><<<dim3(M / TILE, R / TILE), 256, 0, stream>>>(
        Pb, Vt, yb + (size_t)i0 * M, R, M, N, 1.0f);
  }

  // 4. out = y Wo^T (fp32 straight to d_out)
  gemm_bt<float><<<dim3(M / TILE, N / TILE), 256, 0, stream>>>(yb, wob, out, N, M, M, 1.0f);
}

// Round 2
// 979.321 us; speedup vs baseline: 1.0415x; 1.0415x over previous
//
#include <hip/hip_runtime.h>
#include <cstdint>
#include <cstddef>

#define NFRAMES 8192
#define MDIM    1024
#define TILE    128
#define BK      32
#define Q_SCALE 0.06f

typedef __bf16 bf16x8 __attribute__((ext_vector_type(8)));
typedef float  f32x4  __attribute__((ext_vector_type(4)));
typedef unsigned short us8 __attribute__((ext_vector_type(8)));

// fp32 -> bf16 round-to-nearest-even on raw bits
__device__ __forceinline__ unsigned short f2bf(float f) {
  union { float f; uint32_t u; } a; a.f = f;
  uint32_t u = a.u;
  u += 0x7FFFu + ((u >> 16) & 1u);
  return (unsigned short)(u >> 16);
}
__device__ __forceinline__ float bf2f(unsigned short h) {
  union { uint32_t u; float f; } a; a.u = ((uint32_t)h) << 16; return a.f;
}

// async global->LDS, 16B per lane; lds dest is wave-uniform base (HW adds lane*16)
__device__ __forceinline__ void async_ld16(const void* g, void* l) {
  __builtin_amdgcn_global_load_lds(
      (const __attribute__((address_space(1))) void*)(uintptr_t)g,
      (__attribute__((address_space(3))) void*)(uint32_t)(uintptr_t)l,
      16, 0, 0);
}

__device__ __forceinline__ void store_val(float* p, float v) { *p = v; }
__device__ __forceinline__ void store_val(unsigned short* p, float v) { *p = f2bf(v); }

// C[.. x ..] = A * B^T slice:  C[row,col] = sum_{k in [z*kChunk,(z+1)*kChunk)} A[row,k]*B[col,k]
// A row stride lda, B row stride ldb, C row stride ldc; z-partials offset by cz elements.
// m97-style: 128x128 tile, 4 waves 2x2, each wave 4x4 of mfma_f32_16x16x32_bf16.
template <typename OutT>
__global__ __launch_bounds__(256) void gemm_bt(
    const unsigned short* __restrict__ A, int lda,
    const unsigned short* __restrict__ B, int ldb,
    OutT* __restrict__ C, int ldc, long cz,
    int kChunk, float scale)
{
  __shared__ alignas(16) unsigned short As[TILE * BK]; // [row][k] row-major, 8KB
  __shared__ alignas(16) unsigned short Bs[TILE * BK];

  const int tid  = threadIdx.x;
  const int wave = tid >> 6;
  const int lane = tid & 63;
  const int m0 = blockIdx.y * TILE;
  const int n0 = blockIdx.x * TILE;
  const int wm = (wave >> 1) * 64;
  const int wn = (wave & 1) * 64;
  const int kOff = blockIdx.z * kChunk;
  OutT* Cz = C + (size_t)blockIdx.z * cz;

  f32x4 acc[4][4] = {};

  const int q1 = wave * 64 + lane;
  const int q2 = q1 + 256;
  const int r1 = q1 >> 2, c1 = (q1 & 3) << 3;
  const int r2 = q2 >> 2, c2 = (q2 & 3) << 3;

  const int fr = lane & 15;   // row-in-16 (A) / col-in-16 (B) / output col
  const int fq = lane >> 4;   // k-chunk quad / output row quad

  for (int k0 = kOff; k0 < kOff + kChunk; k0 += BK) {
    __syncthreads();
    async_ld16(A + (size_t)(m0 + r1) * lda + k0 + c1, As + wave * 512);
    async_ld16(B + (size_t)(n0 + r1) * ldb + k0 + c1, Bs + wave * 512);
    async_ld16(A + (size_t)(m0 + r2) * lda + k0 + c2, As + 2048 + wave * 512);
    async_ld16(B + (size_t)(n0 + r2) * ldb + k0 + c2, Bs + 2048 + wave * 512);
    __syncthreads();  // implies s_waitcnt vmcnt(0): LDS tiles complete

    bf16x8 af[4], bfr[4];
#pragma unroll
    for (int i = 0; i < 4; ++i)
      af[i] = *(const bf16x8*)&As[(wm + i * 16 + fr) * BK + fq * 8];
#pragma unroll
    for (int j = 0; j < 4; ++j)
      bfr[j] = *(const bf16x8*)&Bs[(wn + j * 16 + fr) * BK + fq * 8];
#pragma unroll
    for (int i = 0; i < 4; ++i)
#pragma unroll
      for (int j = 0; j < 4; ++j)
        acc[i][j] = __builtin_amdgcn_mfma_f32_16x16x32_bf16(af[i], bfr[j], acc[i][j], 0, 0, 0);
  }

  // C/D layout (verified m89/m91): col = lane&15, row = (lane>>4)*4 + reg
#pragma unroll
  for (int i = 0; i < 4; ++i)
#pragma unroll
    for (int j = 0; j < 4; ++j)
#pragma unroll
      for (int r = 0; r < 4; ++r) {
        int row = m0 + wm + i * 16 + fq * 4 + r;
        int col = n0 + wn + j * 16 + fr;
        store_val(&Cz[(size_t)row * ldc + col], acc[i][j][r] * scale);
      }
}

// one block per row: softmax over 8192 cols (bf16 S) + dropout mask, write bf16 P
__global__ __launch_bounds__(256) void softmax_dropout_kernel(
    const unsigned short* __restrict__ S, const float* __restrict__ U,
    unsigned short* __restrict__ P)
{
  const int row = blockIdx.x;
  const us8*    s8 = (const us8*)(S + (size_t)row * NFRAMES);
  const float4* u4 = (const float4*)(U + (size_t)row * NFRAMES);
  us8*          p8 = (us8*)(P + (size_t)row * NFRAMES);
  const int tid = threadIdx.x;
  const int lane = tid & 63, wave = tid >> 6;

  float v[32];
  float mx = -3.4e38f;
#pragma unroll
  for (int j = 0; j < 4; ++j) {
    us8 t = s8[j * 256 + tid];
#pragma unroll
    for (int e = 0; e < 8; ++e) {
      float f = bf2f(t[e]);
      v[j * 8 + e] = f;
      mx = fmaxf(mx, f);
    }
  }
#pragma unroll
  for (int o = 32; o > 0; o >>= 1) mx = fmaxf(mx, __shfl_xor(mx, o));
  __shared__ float redm[4];
  __shared__ float reds[4];
  if (lane == 0) redm[wave] = mx;
  __syncthreads();
  mx = fmaxf(fmaxf(redm[0], redm[1]), fmaxf(redm[2], redm[3]));

  float sum = 0.f;
#pragma unroll
  for (int i = 0; i < 32; ++i) { v[i] = __expf(v[i] - mx); sum += v[i]; }
#pragma unroll
  for (int o = 32; o > 0; o >>= 1) sum += __shfl_xor(sum, o);
  if (lane == 0) reds[wave] = sum;
  __syncthreads();
  sum = reds[0] + reds[1] + reds[2] + reds[3];
  float inv = 1.0f / sum;

#pragma unroll
  for (int j = 0; j < 4; ++j) {
    float4 ua = u4[(j * 256 + tid) * 2];
    float4 ub = u4[(j * 256 + tid) * 2 + 1];
    us8 o;
    o[0] = f2bf(v[j*8+0] * inv * (ua.x >= 0.5f ? 2.0f : 0.0f));
    o[1] = f2bf(v[j*8+1] * inv * (ua.y >= 0.5f ? 2.0f : 0.0f));
    o[2] = f2bf(v[j*8+2] * inv * (ua.z >= 0.5f ? 2.0f : 0.0f));
    o[3] = f2bf(v[j*8+3] * inv * (ua.w >= 0.5f ? 2.0f : 0.0f));
    o[4] = f2bf(v[j*8+4] * inv * (ub.x >= 0.5f ? 2.0f : 0.0f));
    o[5] = f2bf(v[j*8+5] * inv * (ub.y >= 0.5f ? 2.0f : 0.0f));
    o[6] = f2bf(v[j*8+6] * inv * (ub.z >= 0.5f ? 2.0f : 0.0f));
    o[7] = f2bf(v[j*8+7] * inv * (ub.w >= 0.5f ? 2.0f : 0.0f));
    p8[j * 256 + tid] = o;
  }
}

__device__ __forceinline__ void cvt4(const float* in, unsigned short* out, int i, float s) {
  float4 t = ((const float4*)in)[i];
  ushort4 o;
  o.x = f2bf(t.x * s); o.y = f2bf(t.y * s); o.z = f2bf(t.z * s); o.w = f2bf(t.w * s);
  ((ushort4*)out)[i] = o;
}

// one launch converts x + all 4 weights; Wq pre-scaled by Q_SCALE; Wk||Wq concatenated
__global__ __launch_bounds__(256) void cvt_all(
    const float* __restrict__ x, const float* __restrict__ Wk,
    const float* __restrict__ Wq, const float* __restrict__ Wv,
    const float* __restrict__ Wo,
    unsigned short* __restrict__ xb, unsigned short* __restrict__ wkq,
    unsigned short* __restrict__ wvb, unsigned short* __restrict__ wob)
{
  int i = blockIdx.x * 256 + threadIdx.x;  // float4 index
  const int XSZ = (NFRAMES * MDIM) / 4;
  const int WSZ = (MDIM * MDIM) / 4;
  if (i < XSZ) { cvt4(x, xb, i, 1.0f); return; }
  i -= XSZ;
  if (i < WSZ) { cvt4(Wk, wkq, i, 1.0f); return; }
  i -= WSZ;
  if (i < WSZ) { cvt4(Wq, wkq + MDIM * MDIM, i, Q_SCALE); return; }
  i -= WSZ;
  if (i < WSZ) { cvt4(Wv, wvb, i, 1.0f); return; }
  i -= WSZ;
  if (i < WSZ) { cvt4(Wo, wob, i, 1.0f); return; }
}

// yb = bf16(P0 + P1), float4-granular
__global__ __launch_bounds__(256) void reduce2_bf16(
    const float* __restrict__ Ppart, long zstride,
    unsigned short* __restrict__ out, int n4)
{
  int i = blockIdx.x * 256 + threadIdx.x;
  if (i < n4) {
    float4 a = ((const float4*)Ppart)[i];
    float4 b = ((const float4*)(Ppart + zstride))[i];
    ushort4 o;
    o.x = f2bf(a.x + b.x); o.y = f2bf(a.y + b.y);
    o.z = f2bf(a.z + b.z); o.w = f2bf(a.w + b.w);
    ((ushort4*)out)[i] = o;
  }
}

extern "C" void kernel_launch(void* const* d_in, const int* in_sizes, int n_in,
                              void* d_out, int out_size, void* d_ws, size_t ws_size,
                              hipStream_t stream) {
  const float* x  = (const float*)d_in[0];
  const float* Wk = (const float*)d_in[1];
  const float* Wq = (const float*)d_in[2];
  const float* Wv = (const float*)d_in[3];
  const float* Wo = (const float*)d_in[4];
  const float* u  = (const float*)d_in[5];
  float* out = (float*)d_out;

  const int N = NFRAMES, M = MDIM;
  char* base = (char*)d_ws;
  size_t off = 0;
  auto alloc = [&](size_t bytes) -> void* {
    void* p = base + off; off += (bytes + 255) & ~(size_t)255; return p;
  };
  unsigned short* xb  = (unsigned short*)alloc((size_t)N * M * 2);
  unsigned short* wkq = (unsigned short*)alloc((size_t)2 * M * M * 2); // Wk rows then 0.06*Wq rows
  unsigned short* wvb = (unsigned short*)alloc((size_t)M * M * 2);
  unsigned short* wob = (unsigned short*)alloc((size_t)M * M * 2);
  unsigned short* KQb = (unsigned short*)alloc((size_t)N * 2 * M * 2); // [N x 2048]: K | Q
  unsigned short* Vt  = (unsigned short*)alloc((size_t)M * N * 2);     // [M x N] = V^T
  unsigned short* yb  = (unsigned short*)alloc((size_t)N * M * 2);

  // stripe size R over query rows: need S bf16 RxN + P bf16 RxN + Ypart 2*R*M fp32
  size_t avail = ws_size > off ? ws_size - off : 0;
  int R = 128;
  const int cands[7] = {8192, 4096, 2048, 1024, 512, 256, 128};
  for (int ci = 0; ci < 7; ++ci) {
    size_t need = (size_t)cands[ci] * N * 2 + (size_t)cands[ci] * N * 2 +
                  (size_t)2 * cands[ci] * M * 4 + 1024;
    if (need <= avail) { R = cands[ci]; break; }
  }
  unsigned short* Sb = (unsigned short*)alloc((size_t)R * N * 2);
  unsigned short* Pb = (unsigned short*)alloc((size_t)R * N * 2);
  float*          Yp = (float*)alloc((size_t)2 * R * M * 4);

  // 1. convert inputs to bf16 (one launch)
  {
    int total4 = (N * M + 4 * M * M) / 4;
    cvt_all<<<(total4 + 255) / 256, 256, 0, stream>>>(x, Wk, Wq, Wv, Wo, xb, wkq, wvb, wob);
  }

  // 2. projections: [K|Q] = x @ [Wk|0.06Wq]^T  (one GEMM, 1024 blocks); V^T = Wv x^T
  gemm_bt<unsigned short><<<dim3(2 * M / TILE, N / TILE, 1), 256, 0, stream>>>(
      xb, M, wkq, M, KQb, 2 * M, 0, M, 1.0f);
  gemm_bt<unsigned short><<<dim3(N / TILE, M / TILE, 1), 256, 0, stream>>>(
      wvb, M, xb, M, Vt, N, 0, M, 1.0f);

  // 3. attention in row stripes: S = Q K^T (bf16) -> softmax+dropout -> y = P V (split-K=2)
  for (int i0 = 0; i0 < N; i0 += R) {
    gemm_bt<unsigned short><<<dim3(N / TILE, R / TILE, 1), 256, 0, stream>>>(
        KQb + M + (size_t)i0 * 2 * M, 2 * M,   // Q rows i0.., stride 2048
        KQb, 2 * M,                            // K rows, stride 2048
        Sb, N, 0, M, 1.0f);
    softmax_dropout_kernel<<<R, 256, 0, stream>>>(Sb, u + (size_t)i0 * N, Pb);
    gemm_bt<float><<<dim3(M / TILE, R / TILE, 2), 256, 0, stream>>>(
        Pb, N, Vt, N, Yp, M, (long)R * M, N / 2, 1.0f);
    reduce2_bf16<<<(R * M / 4 + 255) / 256, 256, 0, stream>>>(
        Yp, (long)R * M, yb + (size_t)i0 * M, R * M / 4);
  }

  // 4. out = y Wo^T (fp32 straight to d_out)
  gemm_bt<float><<<dim3(M / TILE, N / TILE, 1), 256, 0, stream>>>(
      yb, M, wob, M, out, M, 0, M, 1.0f);
}

// Round 3
// 941.878 us; speedup vs baseline: 1.0829x; 1.0398x over previous
//
#include <hip/hip_runtime.h>
#include <cstdint>
#include <cstddef>

#define NFRAMES 8192
#define MDIM    1024
#define TILE    128
#define BK      32
#define Q_SCALE 0.06f

typedef __bf16 bf16x8 __attribute__((ext_vector_type(8)));
typedef float  f32x4  __attribute__((ext_vector_type(4)));
typedef unsigned short us8 __attribute__((ext_vector_type(8)));

// fp32 -> bf16 round-to-nearest-even on raw bits
__device__ __forceinline__ unsigned short f2bf(float f) {
  union { float f; uint32_t u; } a; a.f = f;
  uint32_t u = a.u;
  u += 0x7FFFu + ((u >> 16) & 1u);
  return (unsigned short)(u >> 16);
}
__device__ __forceinline__ float bf2f(unsigned short h) {
  union { uint32_t u; float f; } a; a.u = ((uint32_t)h) << 16; return a.f;
}

// async global->LDS, 16B per lane; lds dest is wave-uniform base (HW adds lane*16)
__device__ __forceinline__ void async_ld16(const void* g, void* l) {
  __builtin_amdgcn_global_load_lds(
      (const __attribute__((address_space(1))) void*)(uintptr_t)g,
      (__attribute__((address_space(3))) void*)(uint32_t)(uintptr_t)l,
      16, 0, 0);
}

__device__ __forceinline__ void store_val(float* p, float v) { *p = v; }
__device__ __forceinline__ void store_val(unsigned short* p, float v) { *p = f2bf(v); }

// C = A * B^T: C[row,col] = scale * sum_k A[row,k]*B[col,k]
// A row stride lda, B row stride ldb, C row stride ldc.
// m97-style: 128x128 tile, 4 waves 2x2, each wave 4x4 of mfma_f32_16x16x32_bf16.
// swz=1 (requires gridDim.y==64): remap so the 8+ x-blocks sharing an A row-stripe
// get linear ids congruent mod 8 -> same XCD -> A-stripe served from that XCD's L2;
// B-tiles are read by all XCDs in the same window -> LLC-served after first touch.
template <typename OutT>
__global__ __launch_bounds__(256) void gemm_bt(
    const unsigned short* __restrict__ A, int lda,
    const unsigned short* __restrict__ B, int ldb,
    OutT* __restrict__ C, int ldc, int K_, float scale, int swz)
{
  __shared__ alignas(16) unsigned short As[TILE * BK]; // [row][k] row-major, 8KB
  __shared__ alignas(16) unsigned short Bs[TILE * BK];

  const int tid  = threadIdx.x;
  const int wave = tid >> 6;
  const int lane = tid & 63;

  int bx = blockIdx.x, by = blockIdx.y;
  if (swz) {
    int L = blockIdx.x + gridDim.x * blockIdx.y;
    bx = L >> 6;                       // [0, gridX) since gridY==64
    int t = L & 63;
    by = ((t & 7) << 3) | (t >> 3);    // same-by blocks: L%8 == by>>3 (same XCD)
  }
  const int m0 = by * TILE;
  const int n0 = bx * TILE;
  const int wm = (wave >> 1) * 64;
  const int wn = (wave & 1) * 64;

  f32x4 acc[4][4] = {};

  const int q1 = wave * 64 + lane;
  const int q2 = q1 + 256;
  const int r1 = q1 >> 2, c1 = (q1 & 3) << 3;
  const int r2 = q2 >> 2, c2 = (q2 & 3) << 3;

  const int fr = lane & 15;   // row-in-16 (A) / col-in-16 (B) / output col
  const int fq = lane >> 4;   // k-chunk quad / output row quad

  for (int k0 = 0; k0 < K_; k0 += BK) {
    __syncthreads();
    async_ld16(A + (size_t)(m0 + r1) * lda + k0 + c1, As + wave * 512);
    async_ld16(B + (size_t)(n0 + r1) * ldb + k0 + c1, Bs + wave * 512);
    async_ld16(A + (size_t)(m0 + r2) * lda + k0 + c2, As + 2048 + wave * 512);
    async_ld16(B + (size_t)(n0 + r2) * ldb + k0 + c2, Bs + 2048 + wave * 512);
    __syncthreads();  // implies s_waitcnt vmcnt(0): LDS tiles complete

    bf16x8 af[4], bfr[4];
#pragma unroll
    for (int i = 0; i < 4; ++i)
      af[i] = *(const bf16x8*)&As[(wm + i * 16 + fr) * BK + fq * 8];
#pragma unroll
    for (int j = 0; j < 4; ++j)
      bfr[j] = *(const bf16x8*)&Bs[(wn + j * 16 + fr) * BK + fq * 8];
#pragma unroll
    for (int i = 0; i < 4; ++i)
#pragma unroll
      for (int j = 0; j < 4; ++j)
        acc[i][j] = __builtin_amdgcn_mfma_f32_16x16x32_bf16(af[i], bfr[j], acc[i][j], 0, 0, 0);
  }

  // C/D layout (verified m89/m91): col = lane&15, row = (lane>>4)*4 + reg
#pragma unroll
  for (int i = 0; i < 4; ++i)
#pragma unroll
    for (int j = 0; j < 4; ++j)
#pragma unroll
      for (int r = 0; r < 4; ++r) {
        int row = m0 + wm + i * 16 + fq * 4 + r;
        int col = n0 + wn + j * 16 + fr;
        store_val(&C[(size_t)row * ldc + col], acc[i][j][r] * scale);
      }
}

// one block per row: softmax over 8192 cols (bf16 S) + dropout mask, write bf16 P
__global__ __launch_bounds__(256) void softmax_dropout_kernel(
    const unsigned short* __restrict__ S, const float* __restrict__ U,
    unsigned short* __restrict__ P)
{
  const int row = blockIdx.x;
  const us8*    s8 = (const us8*)(S + (size_t)row * NFRAMES);
  const float4* u4 = (const float4*)(U + (size_t)row * NFRAMES);
  us8*          p8 = (us8*)(P + (size_t)row * NFRAMES);
  const int tid = threadIdx.x;
  const int lane = tid & 63, wave = tid >> 6;

  float v[32];
  float mx = -3.4e38f;
#pragma unroll
  for (int j = 0; j < 4; ++j) {
    us8 t = s8[j * 256 + tid];
#pragma unroll
    for (int e = 0; e < 8; ++e) {
      float f = bf2f(t[e]);
      v[j * 8 + e] = f;
      mx = fmaxf(mx, f);
    }
  }
#pragma unroll
  for (int o = 32; o > 0; o >>= 1) mx = fmaxf(mx, __shfl_xor(mx, o));
  __shared__ float redm[4];
  __shared__ float reds[4];
  if (lane == 0) redm[wave] = mx;
  __syncthreads();
  mx = fmaxf(fmaxf(redm[0], redm[1]), fmaxf(redm[2], redm[3]));

  float sum = 0.f;
#pragma unroll
  for (int i = 0; i < 32; ++i) { v[i] = __expf(v[i] - mx); sum += v[i]; }
#pragma unroll
  for (int o = 32; o > 0; o >>= 1) sum += __shfl_xor(sum, o);
  if (lane == 0) reds[wave] = sum;
  __syncthreads();
  sum = reds[0] + reds[1] + reds[2] + reds[3];
  float inv = 1.0f / sum;

#pragma unroll
  for (int j = 0; j < 4; ++j) {
    float4 ua = u4[(j * 256 + tid) * 2];
    float4 ub = u4[(j * 256 + tid) * 2 + 1];
    us8 o;
    o[0] = f2bf(v[j*8+0] * inv * (ua.x >= 0.5f ? 2.0f : 0.0f));
    o[1] = f2bf(v[j*8+1] * inv * (ua.y >= 0.5f ? 2.0f : 0.0f));
    o[2] = f2bf(v[j*8+2] * inv * (ua.z >= 0.5f ? 2.0f : 0.0f));
    o[3] = f2bf(v[j*8+3] * inv * (ua.w >= 0.5f ? 2.0f : 0.0f));
    o[4] = f2bf(v[j*8+4] * inv * (ub.x >= 0.5f ? 2.0f : 0.0f));
    o[5] = f2bf(v[j*8+5] * inv * (ub.y >= 0.5f ? 2.0f : 0.0f));
    o[6] = f2bf(v[j*8+6] * inv * (ub.z >= 0.5f ? 2.0f : 0.0f));
    o[7] = f2bf(v[j*8+7] * inv * (ub.w >= 0.5f ? 2.0f : 0.0f));
    p8[j * 256 + tid] = o;
  }
}

__device__ __forceinline__ void cvt4(const float* in, unsigned short* out, int i, float s) {
  float4 t = ((const float4*)in)[i];
  ushort4 o;
  o.x = f2bf(t.x * s); o.y = f2bf(t.y * s); o.z = f2bf(t.z * s); o.w = f2bf(t.w * s);
  ((ushort4*)out)[i] = o;
}

// one launch converts x + all 4 weights; Wq pre-scaled by Q_SCALE; Wk||Wq concatenated
__global__ __launch_bounds__(256) void cvt_all(
    const float* __restrict__ x, const float* __restrict__ Wk,
    const float* __restrict__ Wq, const float* __restrict__ Wv,
    const float* __restrict__ Wo,
    unsigned short* __restrict__ xb, unsigned short* __restrict__ wkq,
    unsigned short* __restrict__ wvb, unsigned short* __restrict__ wob)
{
  int i = blockIdx.x * 256 + threadIdx.x;  // float4 index
  const int XSZ = (NFRAMES * MDIM) / 4;
  const int WSZ = (MDIM * MDIM) / 4;
  if (i < XSZ) { cvt4(x, xb, i, 1.0f); return; }
  i -= XSZ;
  if (i < WSZ) { cvt4(Wk, wkq, i, 1.0f); return; }
  i -= WSZ;
  if (i < WSZ) { cvt4(Wq, wkq + MDIM * MDIM, i, Q_SCALE); return; }
  i -= WSZ;
  if (i < WSZ) { cvt4(Wv, wvb, i, 1.0f); return; }
  i -= WSZ;
  if (i < WSZ) { cvt4(Wo, wob, i, 1.0f); return; }
}

extern "C" void kernel_launch(void* const* d_in, const int* in_sizes, int n_in,
                              void* d_out, int out_size, void* d_ws, size_t ws_size,
                              hipStream_t stream) {
  const float* x  = (const float*)d_in[0];
  const float* Wk = (const float*)d_in[1];
  const float* Wq = (const float*)d_in[2];
  const float* Wv = (const float*)d_in[3];
  const float* Wo = (const float*)d_in[4];
  const float* u  = (const float*)d_in[5];
  float* out = (float*)d_out;

  const int N = NFRAMES, M = MDIM;
  char* base = (char*)d_ws;
  size_t off = 0;
  auto alloc = [&](size_t bytes) -> void* {
    void* p = base + off; off += (bytes + 255) & ~(size_t)255; return p;
  };
  unsigned short* xb  = (unsigned short*)alloc((size_t)N * M * 2);
  unsigned short* wkq = (unsigned short*)alloc((size_t)2 * M * M * 2); // Wk rows then 0.06*Wq rows
  unsigned short* wvb = (unsigned short*)alloc((size_t)M * M * 2);
  unsigned short* wob = (unsigned short*)alloc((size_t)M * M * 2);
  unsigned short* KQb = (unsigned short*)alloc((size_t)N * 2 * M * 2); // [N x 2048]: K | Q
  unsigned short* Vt  = (unsigned short*)alloc((size_t)M * N * 2);     // [M x N] = V^T
  unsigned short* yb  = (unsigned short*)alloc((size_t)N * M * 2);

  // stripe size R over query rows: need S bf16 RxN + P bf16 RxN
  size_t avail = ws_size > off ? ws_size - off : 0;
  int R = 128;
  const int cands[7] = {8192, 4096, 2048, 1024, 512, 256, 128};
  for (int ci = 0; ci < 7; ++ci) {
    size_t need = (size_t)cands[ci] * N * 2 * 2 + 1024;
    if (need <= avail) { R = cands[ci]; break; }
  }
  unsigned short* Sb = (unsigned short*)alloc((size_t)R * N * 2);
  unsigned short* Pb = (unsigned short*)alloc((size_t)R * N * 2);

  // 1. convert inputs to bf16 (one launch)
  {
    int total4 = (N * M + 4 * M * M) / 4;
    cvt_all<<<(total4 + 255) / 256, 256, 0, stream>>>(x, Wk, Wq, Wv, Wo, xb, wkq, wvb, wob);
  }

  // 2. projections: [K|Q] = x @ [Wk|0.06Wq]^T (one GEMM); V^T = Wv x^T
  gemm_bt<unsigned short><<<dim3(2 * M / TILE, N / TILE), 256, 0, stream>>>(
      xb, M, wkq, M, KQb, 2 * M, M, 1.0f, 1);
  gemm_bt<unsigned short><<<dim3(N / TILE, M / TILE), 256, 0, stream>>>(
      wvb, M, xb, M, Vt, N, M, 1.0f, 0);

  // 3. attention in row stripes: S = Q K^T (bf16) -> softmax+dropout -> y = P V
  const int swzR = (R == N) ? 1 : 0;  // swizzle requires gridDim.y == 64
  for (int i0 = 0; i0 < N; i0 += R) {
    gemm_bt<unsigned short><<<dim3(N / TILE, R / TILE), 256, 0, stream>>>(
        KQb + M + (size_t)i0 * 2 * M, 2 * M,   // Q rows i0.., stride 2048
        KQb, 2 * M,                            // K rows, stride 2048
        Sb, N, M, 1.0f, swzR);
    softmax_dropout_kernel<<<R, 256, 0, stream>>>(Sb, u + (size_t)i0 * N, Pb);
    gemm_bt<unsigned short><<<dim3(M / TILE, R / TILE), 256, 0, stream>>>(
        Pb, N, Vt, N, yb + (size_t)i0 * M, M, N, 1.0f, swzR);
  }

  // 4. out = y Wo^T (fp32 straight to d_out)
  gemm_bt<float><<<dim3(M / TILE, N / TILE), 256, 0, stream>>>(
      yb, M, wob, M, out, M, M, 1.0f, 1);
}

// Round 4
// 905.032 us; speedup vs baseline: 1.1270x; 1.0407x over previous
//
#include <hip/hip_runtime.h>
#include <cstdint>
#include <cstddef>

#define NFRAMES 8192
#define MDIM    1024
#define TILE    128
#define BK      32
#define Q_SCALE 0.06f

typedef __bf16 bf16x8 __attribute__((ext_vector_type(8)));
typedef float  f32x4  __attribute__((ext_vector_type(4)));
typedef unsigned short us8 __attribute__((ext_vector_type(8)));

// fp32 -> bf16 round-to-nearest-even on raw bits
__device__ __forceinline__ unsigned short f2bf(float f) {
  union { float f; uint32_t u; } a; a.f = f;
  uint32_t u = a.u;
  u += 0x7FFFu + ((u >> 16) & 1u);
  return (unsigned short)(u >> 16);
}
__device__ __forceinline__ float bf2f(unsigned short h) {
  union { uint32_t u; float f; } a; a.u = ((uint32_t)h) << 16; return a.f;
}

// async global->LDS, 16B per lane; lds dest is wave-uniform base (HW adds lane*16)
__device__ __forceinline__ void async_ld16(const void* g, void* l) {
  __builtin_amdgcn_global_load_lds(
      (const __attribute__((address_space(1))) void*)(uintptr_t)g,
      (__attribute__((address_space(3))) void*)(uint32_t)(uintptr_t)l,
      16, 0, 0);
}

__device__ __forceinline__ void store_val(float* p, float v) { *p = v; }
__device__ __forceinline__ void store_val(unsigned short* p, float v) { *p = f2bf(v); }

// C = A * B^T slice: C[row,col] = scale * sum_{k in [z*kChunk,(z+1)*kChunk)} A[row,k]*B[col,k]
// z-th partial written at C + z*cz. m97-style 128x128 tile, 4 waves 2x2, 4x4 MFMA/wave.
// swz=1 (requires gridDim.y==64): remap so blocks sharing an A row-stripe get linear
// ids congruent mod 8 -> same XCD -> A-stripe L2-resident; B tiles LLC-served.
template <typename OutT>
__global__ __launch_bounds__(256) void gemm_bt(
    const unsigned short* __restrict__ A, int lda,
    const unsigned short* __restrict__ B, int ldb,
    OutT* __restrict__ C, int ldc, long cz,
    int kChunk, float scale, int swz)
{
  __shared__ alignas(16) unsigned short As[TILE * BK]; // [row][k] row-major, 8KB
  __shared__ alignas(16) unsigned short Bs[TILE * BK];

  const int tid  = threadIdx.x;
  const int wave = tid >> 6;
  const int lane = tid & 63;

  int bx = blockIdx.x, by = blockIdx.y;
  if (swz) {
    int L = blockIdx.x + gridDim.x * blockIdx.y;
    bx = L >> 6;                       // [0, gridX) since gridY==64
    int t = L & 63;
    by = ((t & 7) << 3) | (t >> 3);    // same-by blocks: L%8 == by>>3 (same XCD)
  }
  const int m0 = by * TILE;
  const int n0 = bx * TILE;
  const int wm = (wave >> 1) * 64;
  const int wn = (wave & 1) * 64;
  const int kOff = blockIdx.z * kChunk;
  OutT* Cz = C + (size_t)blockIdx.z * cz;

  f32x4 acc[4][4] = {};

  const int q1 = wave * 64 + lane;
  const int q2 = q1 + 256;
  const int r1 = q1 >> 2, c1 = (q1 & 3) << 3;
  const int r2 = q2 >> 2, c2 = (q2 & 3) << 3;

  const int fr = lane & 15;   // row-in-16 (A) / col-in-16 (B) / output col
  const int fq = lane >> 4;   // k-chunk quad / output row quad

  for (int k0 = kOff; k0 < kOff + kChunk; k0 += BK) {
    __syncthreads();
    async_ld16(A + (size_t)(m0 + r1) * lda + k0 + c1, As + wave * 512);
    async_ld16(B + (size_t)(n0 + r1) * ldb + k0 + c1, Bs + wave * 512);
    async_ld16(A + (size_t)(m0 + r2) * lda + k0 + c2, As + 2048 + wave * 512);
    async_ld16(B + (size_t)(n0 + r2) * ldb + k0 + c2, Bs + 2048 + wave * 512);
    __syncthreads();  // implies s_waitcnt vmcnt(0): LDS tiles complete

    bf16x8 af[4], bfr[4];
#pragma unroll
    for (int i = 0; i < 4; ++i)
      af[i] = *(const bf16x8*)&As[(wm + i * 16 + fr) * BK + fq * 8];
#pragma unroll
    for (int j = 0; j < 4; ++j)
      bfr[j] = *(const bf16x8*)&Bs[(wn + j * 16 + fr) * BK + fq * 8];
#pragma unroll
    for (int i = 0; i < 4; ++i)
#pragma unroll
      for (int j = 0; j < 4; ++j)
        acc[i][j] = __builtin_amdgcn_mfma_f32_16x16x32_bf16(af[i], bfr[j], acc[i][j], 0, 0, 0);
  }

  // C/D layout (verified m89/m91): col = lane&15, row = (lane>>4)*4 + reg
#pragma unroll
  for (int i = 0; i < 4; ++i)
#pragma unroll
    for (int j = 0; j < 4; ++j)
#pragma unroll
      for (int r = 0; r < 4; ++r) {
        int row = m0 + wm + i * 16 + fq * 4 + r;
        int col = n0 + wn + j * 16 + fr;
        store_val(&Cz[(size_t)row * ldc + col], acc[i][j][r] * scale);
      }
}

// one block per row: softmax over 8192 cols (bf16 S) + dropout mask, write bf16 P.
// S and u are read exactly once -> nontemporal (keep LLC space for P, which PV re-reads).
__global__ __launch_bounds__(256) void softmax_dropout_kernel(
    const unsigned short* __restrict__ S, const float* __restrict__ U,
    unsigned short* __restrict__ P)
{
  const int row = blockIdx.x;
  const us8*   s8 = (const us8*)(S + (size_t)row * NFRAMES);
  const f32x4* u4 = (const f32x4*)(U + (size_t)row * NFRAMES);
  us8*         p8 = (us8*)(P + (size_t)row * NFRAMES);
  const int tid = threadIdx.x;
  const int lane = tid & 63, wave = tid >> 6;

  float v[32];
  float mx = -3.4e38f;
#pragma unroll
  for (int j = 0; j < 4; ++j) {
    us8 t = __builtin_nontemporal_load(s8 + j * 256 + tid);
#pragma unroll
    for (int e = 0; e < 8; ++e) {
      float f = bf2f(t[e]);
      v[j * 8 + e] = f;
      mx = fmaxf(mx, f);
    }
  }
#pragma unroll
  for (int o = 32; o > 0; o >>= 1) mx = fmaxf(mx, __shfl_xor(mx, o));
  __shared__ float redm[4];
  __shared__ float reds[4];
  if (lane == 0) redm[wave] = mx;
  __syncthreads();
  mx = fmaxf(fmaxf(redm[0], redm[1]), fmaxf(redm[2], redm[3]));

  float sum = 0.f;
#pragma unroll
  for (int i = 0; i < 32; ++i) { v[i] = __expf(v[i] - mx); sum += v[i]; }
#pragma unroll
  for (int o = 32; o > 0; o >>= 1) sum += __shfl_xor(sum, o);
  if (lane == 0) reds[wave] = sum;
  __syncthreads();
  sum = reds[0] + reds[1] + reds[2] + reds[3];
  float inv = 1.0f / sum;

#pragma unroll
  for (int j = 0; j < 4; ++j) {
    f32x4 ua = __builtin_nontemporal_load(u4 + (j * 256 + tid) * 2);
    f32x4 ub = __builtin_nontemporal_load(u4 + (j * 256 + tid) * 2 + 1);
    us8 o;
    o[0] = f2bf(v[j*8+0] * inv * (ua[0] >= 0.5f ? 2.0f : 0.0f));
    o[1] = f2bf(v[j*8+1] * inv * (ua[1] >= 0.5f ? 2.0f : 0.0f));
    o[2] = f2bf(v[j*8+2] * inv * (ua[2] >= 0.5f ? 2.0f : 0.0f));
    o[3] = f2bf(v[j*8+3] * inv * (ua[3] >= 0.5f ? 2.0f : 0.0f));
    o[4] = f2bf(v[j*8+4] * inv * (ub[0] >= 0.5f ? 2.0f : 0.0f));
    o[5] = f2bf(v[j*8+5] * inv * (ub[1] >= 0.5f ? 2.0f : 0.0f));
    o[6] = f2bf(v[j*8+6] * inv * (ub[2] >= 0.5f ? 2.0f : 0.0f));
    o[7] = f2bf(v[j*8+7] * inv * (ub[3] >= 0.5f ? 2.0f : 0.0f));
    p8[j * 256 + tid] = o;
  }
}

__device__ __forceinline__ void cvt4(const float* in, unsigned short* out, int i, float s) {
  float4 t = ((const float4*)in)[i];
  ushort4 o;
  o.x = f2bf(t.x * s); o.y = f2bf(t.y * s); o.z = f2bf(t.z * s); o.w = f2bf(t.w * s);
  ((ushort4*)out)[i] = o;
}

// one launch converts x + all 4 weights; Wq pre-scaled by Q_SCALE; Wk||Wq concatenated
__global__ __launch_bounds__(256) void cvt_all(
    const float* __restrict__ x, const float* __restrict__ Wk,
    const float* __restrict__ Wq, const float* __restrict__ Wv,
    const float* __restrict__ Wo,
    unsigned short* __restrict__ xb, unsigned short* __restrict__ wkq,
    unsigned short* __restrict__ wvb, unsigned short* __restrict__ wob)
{
  int i = blockIdx.x * 256 + threadIdx.x;  // float4 index
  const int XSZ = (NFRAMES * MDIM) / 4;
  const int WSZ = (MDIM * MDIM) / 4;
  if (i < XSZ) { cvt4(x, xb, i, 1.0f); return; }
  i -= XSZ;
  if (i < WSZ) { cvt4(Wk, wkq, i, 1.0f); return; }
  i -= WSZ;
  if (i < WSZ) { cvt4(Wq, wkq + MDIM * MDIM, i, Q_SCALE); return; }
  i -= WSZ;
  if (i < WSZ) { cvt4(Wv, wvb, i, 1.0f); return; }
  i -= WSZ;
  if (i < WSZ) { cvt4(Wo, wob, i, 1.0f); return; }
}

// yb = bf16(P0 + P1 + P2 + P3), float4-granular; partials read once -> nontemporal
__global__ __launch_bounds__(256) void reduce4_bf16(
    const float* __restrict__ Yp, long zs,
    unsigned short* __restrict__ out, int n4)
{
  int i = blockIdx.x * 256 + threadIdx.x;
  if (i < n4) {
    f32x4 a = __builtin_nontemporal_load((const f32x4*)Yp + i);
    f32x4 b = __builtin_nontemporal_load((const f32x4*)(Yp + zs) + i);
    f32x4 c = __builtin_nontemporal_load((const f32x4*)(Yp + 2 * zs) + i);
    f32x4 d = __builtin_nontemporal_load((const f32x4*)(Yp + 3 * zs) + i);
    ushort4 o;
    o.x = f2bf(a[0] + b[0] + c[0] + d[0]);
    o.y = f2bf(a[1] + b[1] + c[1] + d[1]);
    o.z = f2bf(a[2] + b[2] + c[2] + d[2]);
    o.w = f2bf(a[3] + b[3] + c[3] + d[3]);
    ((ushort4*)out)[i] = o;
  }
}

extern "C" void kernel_launch(void* const* d_in, const int* in_sizes, int n_in,
                              void* d_out, int out_size, void* d_ws, size_t ws_size,
                              hipStream_t stream) {
  const float* x  = (const float*)d_in[0];
  const float* Wk = (const float*)d_in[1];
  const float* Wq = (const float*)d_in[2];
  const float* Wv = (const float*)d_in[3];
  const float* Wo = (const float*)d_in[4];
  const float* u  = (const float*)d_in[5];
  float* out = (float*)d_out;

  const int N = NFRAMES, M = MDIM;
  char* base = (char*)d_ws;
  size_t off = 0;
  auto alloc = [&](size_t bytes) -> void* {
    void* p = base + off; off += (bytes + 255) & ~(size_t)255; return p;
  };
  unsigned short* xb  = (unsigned short*)alloc((size_t)N * M * 2);
  unsigned short* wkq = (unsigned short*)alloc((size_t)2 * M * M * 2); // Wk rows then 0.06*Wq rows
  unsigned short* wvb = (unsigned short*)alloc((size_t)M * M * 2);
  unsigned short* wob = (unsigned short*)alloc((size_t)M * M * 2);
  unsigned short* KQb = (unsigned short*)alloc((size_t)N * 2 * M * 2); // [N x 2048]: K | Q
  unsigned short* Vt  = (unsigned short*)alloc((size_t)M * N * 2);     // [M x N] = V^T
  unsigned short* yb  = (unsigned short*)alloc((size_t)N * M * 2);

  // stripe size R: need S bf16 RxN + P bf16 RxN. Yp (split-K=4 fp32 partials, 16*R*M B)
  // aliases Sb (2*R*N B) -- equal size since 16*M == 2*N; Sb is dead once softmax ran.
  size_t avail = ws_size > off ? ws_size - off : 0;
  int R = 128;
  const int cands[7] = {8192, 4096, 2048, 1024, 512, 256, 128};
  for (int ci = 0; ci < 7; ++ci) {
    size_t need = (size_t)cands[ci] * N * 2 * 2 + 1024;
    if (need <= avail) { R = cands[ci]; break; }
  }
  unsigned short* Sb = (unsigned short*)alloc((size_t)R * N * 2);
  unsigned short* Pb = (unsigned short*)alloc((size_t)R * N * 2);
  float* Yp = (float*)Sb;  // alias: PV split-K partials overwrite dead S stripe

  // 1. convert inputs to bf16 (one launch)
  {
    int total4 = (N * M + 4 * M * M) / 4;
    cvt_all<<<(total4 + 255) / 256, 256, 0, stream>>>(x, Wk, Wq, Wv, Wo, xb, wkq, wvb, wob);
  }

  // 2. projections: [K|Q] = x @ [Wk|0.06Wq]^T (one GEMM); V^T = Wv x^T
  gemm_bt<unsigned short><<<dim3(2 * M / TILE, N / TILE), 256, 0, stream>>>(
      xb, M, wkq, M, KQb, 2 * M, 0, M, 1.0f, 1);
  gemm_bt<unsigned short><<<dim3(N / TILE, M / TILE), 256, 0, stream>>>(
      wvb, M, xb, M, Vt, N, 0, M, 1.0f, 0);

  // 3. attention stripes: S = Q K^T (bf16) -> softmax+dropout -> y = P V (split-K=4)
  const int swzR = (R == N) ? 1 : 0;  // swizzle requires gridDim.y == 64
  for (int i0 = 0; i0 < N; i0 += R) {
    gemm_bt<unsigned short><<<dim3(N / TILE, R / TILE), 256, 0, stream>>>(
        KQb + M + (size_t)i0 * 2 * M, 2 * M,   // Q rows i0.., stride 2048
        KQb, 2 * M,                            // K rows, stride 2048
        Sb, N, 0, M, 1.0f, swzR);
    softmax_dropout_kernel<<<R, 256, 0, stream>>>(Sb, u + (size_t)i0 * N, Pb);
    gemm_bt<float><<<dim3(M / TILE, R / TILE, 4), 256, 0, stream>>>(
        Pb, N, Vt, N, Yp, M, (long)R * M, N / 4, 1.0f, swzR);
    reduce4_bf16<<<(R * M / 4 + 255) / 256, 256, 0, stream>>>(
        Yp, (long)R * M, yb + (size_t)i0 * M, R * M / 4);
  }

  // 4. out = y Wo^T (fp32 straight to d_out)
  gemm_bt<float><<<dim3(M / TILE, N / TILE), 256, 0, stream>>>(
      yb, M, wob, M, out, M, 0, M, 1.0f, 1);
}